// Round 8
// baseline (85.845 us; speedup 1.0000x reference)
//
#include <hip/hip_runtime.h>

#define HH 512
#define WW 512
#define HW (HH * WW)
#define RR 5
#define KS 11
#define EPS_F 1e-5f
#define NLOG2E 1.44269504088896340736f
#define OPW 54                // outputs per wave in x (64 lanes - 10 halo)
#define NG 10                 // column groups: 9*54 + overlap group at 458
#define RPW 3                 // output rows per wave
#define NR (KS + RPW - 1)     // 13 input rows per wave
#define RPB (4 * RPW)         // 12 rows per block
#define GY ((HH + RPB - 1) / RPB)  // 43 (last block overhangs, masked)

typedef float f2 __attribute__((ext_vector_type(2)));
__device__ __forceinline__ f2 fma2(f2 a, f2 b, f2 c) { return __builtin_elementwise_fma(a, b, c); }

// R17 = R16 (81.6) with RPW 2->3. Model: dur_us ~= ~70us fixed harness work
// (268MB re-poison fill @ 82% HBM + reset memsets) + ~11.6us kernel. Ledger:
// only per-output redundancy still pays (R16: -1.7us); all structural levers
// (barriers, staging, VMEM shape) are exhausted at +-1us.
// 13 input rows (load + rcp/exp2 + power chain) shared by 3 output rows:
// loads/output 6->4.33 rows, trans chains/output -28%, VALU/output -11%
// (accum is the irreducible floor: 165 pk-ops/output). Zero __syncthreads.
// VGPR: 36 f2 accum = 72 + pipeline temps ~115 < 128 cap (256,4); LDS 24KB,
// 16 waves/CU. grid.y=43: last block's rows 512-515 ride the boundary path
// (clamped loads, y<HH store mask).
// Stop-rule: |delta| <= 1us -> harness-fill roofline, declare ROOFLINE next.
__global__ __launch_bounds__(256, 4) void gauss_psf_kernel(const float* __restrict__ image,
                                                           const float* __restrict__ psf,
                                                           float* __restrict__ out) {
    __shared__ float4 smH[4][6][64];    // per-wave private class planes, 24 KB

    const int lane = threadIdx.x;            // 0..63
    const int ty   = threadIdx.y;            // 0..3 (wave id in block)
    const int g    = blockIdx.x;             // 0..9 column group
    const int by   = blockIdx.y;             // 0..42 (12 rows per block)
    const int yA   = by * RPB + ty * RPW;    // wave's first output row
    const int b    = blockIdx.z;

    const int c0   = (g == NG - 1) ? (WW - OPW) : g * OPW;
    const int col  = c0 - RR + lane;         // this lane's column
    const int colc = col < 0 ? 0 : (col > WW - 1 ? WW - 1 : col);
    const float xm = ((unsigned)col < (unsigned)WW) ? 1.0f : 0.0f;

    const float* pw   = psf + (size_t)b * HW;
    const float* img0 = image + (size_t)b * 3 * HW;

    // ---- accumulators: rows A,B,C x 6 class pairs x (ch0,ch1,ch2,w) ----
    f2 A0[3], A1[3], A2[3], Aw[3];
    f2 B0[3], B1[3], B2[3], Bw[3];
    f2 C0[3], C1[3], C2[3], Cw[3];
#pragma unroll
    for (int p = 0; p < 3; ++p) {
        A0[p] = (f2)0.0f; A1[p] = (f2)0.0f; A2[p] = (f2)0.0f; Aw[p] = (f2)0.0f;
        B0[p] = (f2)0.0f; B1[p] = (f2)0.0f; B2[p] = (f2)0.0f; Bw[p] = (f2)0.0f;
        C0[p] = (f2)0.0f; C1[p] = (f2)0.0f; C2[p] = (f2)0.0f; Cw[p] = (f2)0.0f;
    }

    auto accum = [&](f2 (&a0)[3], f2 (&a1)[3], f2 (&a2)[3], f2 (&aw)[3],
                     float u, float t, float t4, float t9, float t16, float t25,
                     float i0, float i1, float i2) {
        const f2 u2  = {u, u};
        const f2 f01 = u2 * (f2){1.0f, t};                 // t^(i^2+{0,1})
        const f2 f23 = u2 * (f2){t4, t9};                  // t^(i^2+{4,9})
        const f2 f45 = u2 * (f2){t16, t25};                // t^(i^2+{16,25})
        const f2 i0v = {i0, i0}, i1v = {i1, i1}, i2v = {i2, i2};
        a0[0] = fma2(i0v, f01, a0[0]);
        a0[1] = fma2(i0v, f23, a0[1]);
        a0[2] = fma2(i0v, f45, a0[2]);
        a1[0] = fma2(i1v, f01, a1[0]);
        a1[1] = fma2(i1v, f23, a1[1]);
        a1[2] = fma2(i1v, f45, a1[2]);
        a2[0] = fma2(i2v, f01, a2[0]);
        a2[1] = fma2(i2v, f23, a2[1]);
        a2[2] = fma2(i2v, f45, a2[2]);
        aw[0] += f01;
        aw[1] += f23;
        aw[2] += f45;
    };

    // shared row pipeline: powers once per input row, consumed by up to 3 rows
    auto row = [&](int r, float t, float i0, float i1, float i2) {
        const float t2 = t * t, t4 = t2 * t2, t8 = t4 * t4;
        const float t9 = t8 * t, t16 = t8 * t8, t25 = t16 * t9;
        if (r <= KS - 1) {                                 // A: rows 0..10
            const int ii = (r - RR) * (r - RR);            // constexpr after unroll
            const float u = ii == 0 ? 1.0f : ii == 1 ? t : ii == 4 ? t4
                          : ii == 9 ? t9 : ii == 16 ? t16 : t25;
            accum(A0, A1, A2, Aw, u, t, t4, t9, t16, t25, i0, i1, i2);
        }
        if (r >= 1 && r <= KS) {                           // B: rows 1..11
            const int ii = (r - 1 - RR) * (r - 1 - RR);
            const float u = ii == 0 ? 1.0f : ii == 1 ? t : ii == 4 ? t4
                          : ii == 9 ? t9 : ii == 16 ? t16 : t25;
            accum(B0, B1, B2, Bw, u, t, t4, t9, t16, t25, i0, i1, i2);
        }
        if (r >= 2) {                                      // C: rows 2..12
            const int ii = (r - 2 - RR) * (r - 2 - RR);
            const float u = ii == 0 ? 1.0f : ii == 1 ? t : ii == 4 ? t4
                          : ii == 9 ? t9 : ii == 16 ? t16 : t25;
            accum(C0, C1, C2, Cw, u, t, t4, t9, t16, t25, i0, i1, i2);
        }
    };

    if (g >= 1 && g <= 8 && by >= 1 && by <= 41) {
        // fully interior (x and y): no clamps, no masks; imm-offset row walk
        const float* pb = img0 + (size_t)(yA - RR) * WW + col;
        const float* wb = pw + (size_t)(yA - RR) * WW + col;
#pragma unroll
        for (int r = 0; r < NR; ++r) {
            const float w  = wb[r * WW];
            const float i0 = pb[r * WW];
            const float i1 = pb[r * WW + HW];
            const float i2 = pb[r * WW + 2 * HW];
            const float a = -NLOG2E * __builtin_amdgcn_rcpf(fmaf(2.0f * w, w, EPS_F));
            const float t = __builtin_amdgcn_exp2f(a);
            row(r, t, i0, i1, i2);
        }
    } else {
        // boundary blocks: per-row clamp + mask, per-lane x mask
#pragma unroll
        for (int r = 0; r < NR; ++r) {
            const int gy = yA - RR + r;
            const int ry = gy < 0 ? 0 : (gy > HH - 1 ? HH - 1 : gy);
            const float ym = ((unsigned)gy < (unsigned)HH) ? 1.0f : 0.0f;
            const int ni = ry * WW + colc;
            const float w  = pw[ni];
            const float i0 = img0[ni];
            const float i1 = img0[ni + HW];
            const float i2 = img0[ni + 2 * HW];
            const float a = -NLOG2E * __builtin_amdgcn_rcpf(fmaf(2.0f * w, w, EPS_F));
            const float t = xm * ym * __builtin_amdgcn_exp2f(a);
            row(r, t, i0, i1, i2);
        }
    }

    // ---- Pass H (x3, same per-wave scratch; same-wave DS ops are in-order,
    //      compiler lgkmcnt handles RAW — no barrier anywhere) ----
    const int lm = lane - RR;
    const int lb = lm < 0 ? 0 : (lm > OPW - 1 ? OPW - 1 : lm);
    float* outb = out + (size_t)b * 3 * HW;

    auto passH = [&](f2 (&a0)[3], f2 (&a1)[3], f2 (&a2)[3], f2 (&aw)[3], int y) {
#pragma unroll
        for (int p = 0; p < 3; ++p) {                      // 6 ds_write_b128
            smH[ty][2 * p][lane]     = make_float4(a0[p].x, a1[p].x, a2[p].x, aw[p].x);
            smH[ty][2 * p + 1][lane] = make_float4(a0[p].y, a1[p].y, a2[p].y, aw[p].y);
        }
        f2 s01 = (f2)0.0f, s2w = (f2)0.0f;
#pragma unroll
        for (int j = 0; j < KS; ++j) {
            const int jj = (j - RR) * (j - RR);            // constexpr
            const int ai = jj == 0 ? 0 : jj == 1 ? 1 : jj == 4 ? 2
                         : jj == 9 ? 3 : jj == 16 ? 4 : 5;
            const float4 v = smH[ty][ai][lb + j];          // ds_read_b128, imm off
            s01 += (f2){v.x, v.y};                         // pk_add
            s2w += (f2){v.z, v.w};
        }
        if ((unsigned)lm < OPW && y < HH) {                // lanes 5..58 store
            const float swv = s2w.y;                       // >= 1 (center tap)
            float inv = __builtin_amdgcn_rcpf(swv);
            inv = inv * (2.0f - swv * inv);                // Newton: ~1e-7 rel
            const int oi = y * WW + col;                   // col in [0,511] here
            outb[oi]          = s01.x * inv;
            outb[HW + oi]     = s01.y * inv;
            outb[2 * HW + oi] = s2w.x * inv;
        }
    };

    passH(A0, A1, A2, Aw, yA);
    passH(B0, B1, B2, Bw, yA + 1);
    passH(C0, C1, C2, Cw, yA + 2);
}

extern "C" void kernel_launch(void* const* d_in, const int* in_sizes, int n_in,
                              void* d_out, int out_size, void* d_ws, size_t ws_size,
                              hipStream_t stream) {
    const float* image = (const float*)d_in[0];
    const float* psf   = (const float*)d_in[1];
    float* out = (float*)d_out;

    dim3 block(64, 4, 1);                  // 4 independent waves, zero barriers
    dim3 grid(NG, GY, 4);                  // 10 x 43 x 4 = 1720 blocks
    gauss_psf_kernel<<<grid, block, 0, stream>>>(image, psf, out);
}

// Round 9
// 81.712 us; speedup vs baseline: 1.0506x; 1.0506x over previous
//
#include <hip/hip_runtime.h>

#define HH 512
#define WW 512
#define HW (HH * WW)
#define RR 5
#define KS 11
#define EPS_F 1e-5f
#define NLOG2E 1.44269504088896340736f
#define OPW 54                // outputs per wave in x (64 lanes - 10 halo)
#define NG 10                 // column groups: 9*54 + overlap group at 458
#define RPW 2                 // output rows per wave
#define NR (KS + RPW - 1)     // 12 input rows per wave

typedef float f2 __attribute__((ext_vector_type(2)));
__device__ __forceinline__ f2 fma2(f2 a, f2 b, f2 c) { return __builtin_elementwise_fma(a, b, c); }

// R18 = R16 verbatim (revert of R17). Final ledger: RPW=3 (R17) regressed
// +4.2us via VGPR pressure (36 f2 accum + 13-deep pipeline > 128 cap);
// RPW=2 is the measured optimum of the redundancy/register trade.
// Model: dur_us ~= ~70us fixed harness work (268MB re-poison fill @ 75-83%
// HBM — its own roofline — + reset memsets) + ~11.6us kernel. Kernel floor:
// 165 pk-ops/output accumulation (~4-5us) + 24 loads/output; both remaining
// levers (more sharing, more staging) measurably backfire on occupancy.
// Structure: zero __syncthreads; wave = 2 output rows x 54 cols; 12 input
// rows (load + rcp/exp2 + power chain) shared between both rows; pass H x2
// through per-wave private LDS scratch (same-wave DS in-order via lgkmcnt).
__global__ __launch_bounds__(256, 4) void gauss_psf_kernel(const float* __restrict__ image,
                                                           const float* __restrict__ psf,
                                                           float* __restrict__ out) {
    __shared__ float4 smH[4][6][64];    // per-wave private class planes, 24 KB

    const int lane = threadIdx.x;            // 0..63
    const int ty   = threadIdx.y;            // 0..3 (wave id in block)
    const int g    = blockIdx.x;             // 0..9 column group
    const int by   = blockIdx.y;             // 0..63 (8 rows per block)
    const int yA   = by * (4 * RPW) + ty * RPW;  // wave's first output row
    const int b    = blockIdx.z;

    const int c0   = (g == NG - 1) ? (WW - OPW) : g * OPW;
    const int col  = c0 - RR + lane;         // this lane's column
    const int colc = col < 0 ? 0 : (col > WW - 1 ? WW - 1 : col);
    const float xm = ((unsigned)col < (unsigned)WW) ? 1.0f : 0.0f;

    const float* pw   = psf + (size_t)b * HW;
    const float* img0 = image + (size_t)b * 3 * HW;

    // ---- accumulators: rows A and B, 6 class pairs x (ch0,ch1,ch2,w) ----
    f2 A0[3], A1[3], A2[3], Aw[3], B0[3], B1[3], B2[3], Bw[3];
#pragma unroll
    for (int p = 0; p < 3; ++p) {
        A0[p] = (f2)0.0f; A1[p] = (f2)0.0f; A2[p] = (f2)0.0f; Aw[p] = (f2)0.0f;
        B0[p] = (f2)0.0f; B1[p] = (f2)0.0f; B2[p] = (f2)0.0f; Bw[p] = (f2)0.0f;
    }

    auto accum = [&](f2 (&a0)[3], f2 (&a1)[3], f2 (&a2)[3], f2 (&aw)[3],
                     float u, float t, float t4, float t9, float t16, float t25,
                     float i0, float i1, float i2) {
        const f2 u2  = {u, u};
        const f2 f01 = u2 * (f2){1.0f, t};                 // t^(i^2+{0,1})
        const f2 f23 = u2 * (f2){t4, t9};                  // t^(i^2+{4,9})
        const f2 f45 = u2 * (f2){t16, t25};                // t^(i^2+{16,25})
        const f2 i0v = {i0, i0}, i1v = {i1, i1}, i2v = {i2, i2};
        a0[0] = fma2(i0v, f01, a0[0]);
        a0[1] = fma2(i0v, f23, a0[1]);
        a0[2] = fma2(i0v, f45, a0[2]);
        a1[0] = fma2(i1v, f01, a1[0]);
        a1[1] = fma2(i1v, f23, a1[1]);
        a1[2] = fma2(i1v, f45, a1[2]);
        a2[0] = fma2(i2v, f01, a2[0]);
        a2[1] = fma2(i2v, f23, a2[1]);
        a2[2] = fma2(i2v, f45, a2[2]);
        aw[0] += f01;
        aw[1] += f23;
        aw[2] += f45;
    };

    // shared row pipeline: powers computed once, consumed by A (r<=10) and B (r>=1)
    auto row = [&](int r, float t, float i0, float i1, float i2) {
        const float t2 = t * t, t4 = t2 * t2, t8 = t4 * t4;
        const float t9 = t8 * t, t16 = t8 * t8, t25 = t16 * t9;
        if (r <= KS - 1) {
            const int ii = (r - RR) * (r - RR);            // constexpr after unroll
            const float u = ii == 0 ? 1.0f : ii == 1 ? t : ii == 4 ? t4
                          : ii == 9 ? t9 : ii == 16 ? t16 : t25;
            accum(A0, A1, A2, Aw, u, t, t4, t9, t16, t25, i0, i1, i2);
        }
        if (r >= 1) {
            const int ii = (r - 1 - RR) * (r - 1 - RR);    // constexpr after unroll
            const float u = ii == 0 ? 1.0f : ii == 1 ? t : ii == 4 ? t4
                          : ii == 9 ? t9 : ii == 16 ? t16 : t25;
            accum(B0, B1, B2, Bw, u, t, t4, t9, t16, t25, i0, i1, i2);
        }
    };

    if (g >= 1 && g <= 8 && by >= 1 && by <= 62) {
        // fully interior (x and y): no clamps, no masks; imm-offset row walk
        const float* pb = img0 + (size_t)(yA - RR) * WW + col;
        const float* wb = pw + (size_t)(yA - RR) * WW + col;
#pragma unroll
        for (int r = 0; r < NR; ++r) {
            const float w  = wb[r * WW];
            const float i0 = pb[r * WW];
            const float i1 = pb[r * WW + HW];
            const float i2 = pb[r * WW + 2 * HW];
            const float a = -NLOG2E * __builtin_amdgcn_rcpf(fmaf(2.0f * w, w, EPS_F));
            const float t = __builtin_amdgcn_exp2f(a);
            row(r, t, i0, i1, i2);
        }
    } else {
        // boundary blocks: per-row clamp + mask, per-lane x mask
#pragma unroll
        for (int r = 0; r < NR; ++r) {
            const int gy = yA - RR + r;
            const int ry = gy < 0 ? 0 : (gy > HH - 1 ? HH - 1 : gy);
            const float ym = ((unsigned)gy < (unsigned)HH) ? 1.0f : 0.0f;
            const int ni = ry * WW + colc;
            const float w  = pw[ni];
            const float i0 = img0[ni];
            const float i1 = img0[ni + HW];
            const float i2 = img0[ni + 2 * HW];
            const float a = -NLOG2E * __builtin_amdgcn_rcpf(fmaf(2.0f * w, w, EPS_F));
            const float t = xm * ym * __builtin_amdgcn_exp2f(a);
            row(r, t, i0, i1, i2);
        }
    }

    // ---- Pass H (twice, same per-wave scratch; same-wave DS ops are in-order,
    //      compiler lgkmcnt handles RAW — no barrier anywhere) ----
    const int lm = lane - RR;
    const int lb = lm < 0 ? 0 : (lm > OPW - 1 ? OPW - 1 : lm);
    float* outb = out + (size_t)b * 3 * HW;

    auto passH = [&](f2 (&a0)[3], f2 (&a1)[3], f2 (&a2)[3], f2 (&aw)[3], int y) {
#pragma unroll
        for (int p = 0; p < 3; ++p) {                      // 6 ds_write_b128
            smH[ty][2 * p][lane]     = make_float4(a0[p].x, a1[p].x, a2[p].x, aw[p].x);
            smH[ty][2 * p + 1][lane] = make_float4(a0[p].y, a1[p].y, a2[p].y, aw[p].y);
        }
        f2 s01 = (f2)0.0f, s2w = (f2)0.0f;
#pragma unroll
        for (int j = 0; j < KS; ++j) {
            const int jj = (j - RR) * (j - RR);            // constexpr
            const int ai = jj == 0 ? 0 : jj == 1 ? 1 : jj == 4 ? 2
                         : jj == 9 ? 3 : jj == 16 ? 4 : 5;
            const float4 v = smH[ty][ai][lb + j];          // ds_read_b128, imm off
            s01 += (f2){v.x, v.y};                         // pk_add
            s2w += (f2){v.z, v.w};
        }
        if ((unsigned)lm < OPW) {                          // lanes 5..58 store
            const float swv = s2w.y;                       // >= 1 (center tap)
            float inv = __builtin_amdgcn_rcpf(swv);
            inv = inv * (2.0f - swv * inv);                // Newton: ~1e-7 rel
            const int oi = y * WW + col;                   // col in [0,511] here
            outb[oi]          = s01.x * inv;
            outb[HW + oi]     = s01.y * inv;
            outb[2 * HW + oi] = s2w.x * inv;
        }
    };

    passH(A0, A1, A2, Aw, yA);
    passH(B0, B1, B2, Bw, yA + 1);
}

extern "C" void kernel_launch(void* const* d_in, const int* in_sizes, int n_in,
                              void* d_out, int out_size, void* d_ws, size_t ws_size,
                              hipStream_t stream) {
    const float* image = (const float*)d_in[0];
    const float* psf   = (const float*)d_in[1];
    float* out = (float*)d_out;

    dim3 block(64, 4, 1);                  // 4 independent waves, zero barriers
    dim3 grid(NG, HH / (4 * RPW), 4);      // 10 x 64 x 4 = 2560 blocks
    gauss_psf_kernel<<<grid, block, 0, stream>>>(image, psf, out);
}